// Round 20
// baseline (198.947 us; speedup 1.0000x reference)
//
#include <hip/hip_runtime.h>

// MACE node message block. All-MFMA, bf16 intermediates, cvt_pk, natural-order
// edge MLP. 7 GPU ops: memset -> k1(pack|hist) -> k2(scan|node_up)
// -> k_scatter -> k_edge -> k_gather -> k_node_out.
// (R19 lesson: scatter and edge MLP have conflicting memory personalities --
//  merging them into one launch cost 25us; separate launches win.)
// N=10000, E=160000, C=128, RB=8, HID=64.
//
// ws layout (float units):
//   [0 .. 2.56M)        svp (N,128) uint2 packed bf16 [se,ve0|ve1,ve2]
//   [2.56M .. 7.68M)    msg (N,1024) bf16; cnt/cursor ints live here pre-gather
//   [7.68M .. +69632)   packed bf16 weights: W2p W3p W4p Wlsp Wlvp Wusp Wuvp
//   [7749632 +10001]    row (int)
//   [7759636 +160000]   elist (int)  sorted pos -> edge id
//   [7919636 +160000]   snds (int)
//   [8079636 +640000]   eas (float4)
//   [8719636 +20.48Mf)  tpw [edge][512] bf16 (164 MB)

#define N_NODES 10000
#define N_EDGES 160000

#define SVP_OFF    0u
#define MSG_OFF    2560000u
#define WP_OFF     7680000u
#define ROW_OFF    7749632u
#define ELIST_OFF  7759636u
#define SNDS_OFF   7919636u
#define EAS_OFF    8079636u
#define TPW_OFF    8719636u

// k1 block partition (512 threads each)
#define K1_PACK    272                  // 272*512 = 139264 pack elements
#define K1_HIST    313                  // 313*512 >= 160000

typedef __attribute__((ext_vector_type(8))) short bf16x8;
typedef __attribute__((ext_vector_type(4))) float f32x4;

__device__ __forceinline__ float silu(float x) {
    return x / (1.0f + __expf(-x));
}
__device__ __forceinline__ short f2bf(float x) {
    unsigned u = __float_as_uint(x);
    unsigned r = (u + 0x7FFFu + ((u >> 16) & 1u)) >> 16;
    return (short)r;
}
// HW packed f32->bf16 (RNE), single instruction; no builtin on gfx950.
__device__ __forceinline__ unsigned cvtpk(float lo, float hi) {
    unsigned r;
    asm("v_cvt_pk_bf16_f32 %0, %1, %2" : "=v"(r) : "v"(lo), "v"(hi));
    return r;
}
__device__ __forceinline__ float bf2f(unsigned h) {
    return __uint_as_float(h << 16);
}

constexpr float INV_SQRT_C  = 0.08838834764831845f;
constexpr float INV_SQRT_RB = 0.35355339059327373f;
constexpr float INV_SQRT_H  = 0.125f;
constexpr float OUT_SCALE   = 0.0625f * 0.0625f;      // 1/sqrt(256) / AVG_NEIGH
constexpr float C000 = 0.7071067811865476f;
constexpr float C110 = 0.4082482904638631f;
constexpr float C011 = 0.7071067811865476f;
constexpr float C101 = 0.7071067811865476f;

// ---------------- K1: pack | hist ----------
// shorts: W2p[0,4096) W3p[4096,8192) W4p[8192,40960) Wlsp[40960,73728)
//         Wlvp[73728,106496) Wusp[106496,122880) Wuvp[122880,139264)
__global__ __launch_bounds__(512) void k1_pack_hist(
    const float* __restrict__ W2, const float* __restrict__ W3,
    const float* __restrict__ W4,
    const float* __restrict__ Wls, const float* __restrict__ Wlv,
    const float* __restrict__ Wus, const float* __restrict__ Wuv,
    short* __restrict__ Wp,
    const int* __restrict__ ei, int* __restrict__ cnt) {
    const int bid = blockIdx.x;
    const int tid = threadIdx.x;

    if (bid < K1_PACK) {
        int idx = bid * 512 + tid;          // < 139264
        if (idx < 4096) {
            int i2 = idx;
            int e = i2 & 7, l = (i2 >> 3) & 63, kt = (i2 >> 9) & 1, nt = i2 >> 10;
            int k = kt * 32 + (l >> 4) * 8 + e;
            int col = nt * 16 + (l & 15);
            Wp[idx] = f2bf(W2[k * 64 + col] * INV_SQRT_H);
        } else if (idx < 8192) {
            int i2 = idx - 4096;
            int e = i2 & 7, l = (i2 >> 3) & 63, kt = (i2 >> 9) & 1, nt = i2 >> 10;
            int k = kt * 32 + (l >> 4) * 8 + e;
            int col = nt * 16 + (l & 15);
            Wp[idx] = f2bf(W3[k * 64 + col] * INV_SQRT_H);
        } else if (idx < 40960) {
            int i2 = idx - 8192;
            int e = i2 & 7, l = (i2 >> 3) & 63, kt = (i2 >> 9) & 1, nt = i2 >> 10;
            int k = kt * 32 + (l >> 4) * 8 + e;
            int o = nt * 16 + (l & 15);      // o = c*4 + a
            int c = o >> 2, a = o & 3;
            Wp[idx] = f2bf(W4[k * 512 + a * 128 + c] * INV_SQRT_H);
        } else if (idx < 73728) {
            int i2 = idx - 40960;
            int e = i2 & 7, l = (i2 >> 3) & 63, kt = (i2 >> 9) & 7, nt = (i2 >> 12) & 7;
            int k = kt * 32 + (l >> 4) * 8 + e;
            int d = nt * 16 + (l & 15);
            Wp[idx] = f2bf(Wls[k * 128 + d] * OUT_SCALE);
        } else if (idx < 106496) {
            int i2 = idx - 73728;
            int e = i2 & 7, l = (i2 >> 3) & 63, kt = (i2 >> 9) & 7, nt = (i2 >> 12) & 7;
            int k = kt * 32 + (l >> 4) * 8 + e;
            int d = nt * 16 + (l & 15);
            Wp[idx] = f2bf(Wlv[k * 128 + d] * OUT_SCALE);
        } else if (idx < 122880) {
            int i2 = idx - 106496;
            int e = i2 & 7, l = (i2 >> 3) & 63, kt = (i2 >> 9) & 3, nt = (i2 >> 11) & 7;
            int k = kt * 32 + (l >> 4) * 8 + e;
            int d = nt * 16 + (l & 15);
            Wp[idx] = f2bf(Wus[k * 128 + d] * INV_SQRT_C);
        } else if (idx < 139264) {
            int i2 = idx - 122880;
            int e = i2 & 7, l = (i2 >> 3) & 63, kt = (i2 >> 9) & 3, nt = (i2 >> 11) & 7;
            int k = kt * 32 + (l >> 4) * 8 + e;
            int d = nt * 16 + (l & 15);
            Wp[idx] = f2bf(Wuv[k * 128 + d] * INV_SQRT_C);
        }
        return;
    }
    // ---- receiver histogram
    int e = (bid - K1_PACK) * 512 + tid;
    if (e < N_EDGES) atomicAdd(&cnt[ei[N_EDGES + e]], 1);
}

// ---------------- K2: scan (block 0) | node_up (blocks 1..625) --------------
__global__ __launch_bounds__(512) void k2_scan_nodeup(
    const int*   __restrict__ cnt,
    int*         __restrict__ row,
    int*         __restrict__ cursor,
    const float* __restrict__ nf,
    const short* __restrict__ Wp,
    uint2*       __restrict__ svp) {
    __shared__ __align__(8) short stage[16 * 128 * 4];   // 16KB (scan reuses as int)
    const int bid = blockIdx.x;
    const int tid = threadIdx.x;

    if (bid == 0) {
        int* part = (int*)stage;
        const int t = tid;
        const int base = t * 20;
        int s = 0;
        #pragma unroll
        for (int i = 0; i < 20; ++i) {
            int idx = base + i;
            s += (idx < N_NODES) ? cnt[idx] : 0;
        }
        part[t] = s;
        __syncthreads();
        for (int off = 1; off < 512; off <<= 1) {
            int v = (t >= off) ? part[t - off] : 0;
            __syncthreads();
            part[t] += v;
            __syncthreads();
        }
        int run = part[t] - s;   // exclusive prefix
        #pragma unroll
        for (int i = 0; i < 20; ++i) {
            int idx = base + i;
            if (idx < N_NODES) {
                row[idx] = run;
                cursor[idx] = run;
                run += cnt[idx];
            }
        }
        if (t == 511) row[N_NODES] = part[511];
        return;
    }

    // ---- node up-projection (MFMA) -> svp
    const short* Wusp = Wp + 106496;
    const short* Wuvp = Wp + 122880;
    const int l   = tid & 63;
    const int w   = tid >> 6;
    const int sec = w & 3;
    const int nth = w >> 2;
    const int r16 = l & 15;
    const int g4  = l >> 4;
    const int n0  = (bid - 1) * 16;
    const float* nfrow = nf + (size_t)(n0 + r16) * 512;

    bf16x8 a[4];
    if (sec == 0) {
        #pragma unroll
        for (int kt = 0; kt < 4; ++kt) {
            const float* p = nfrow + kt * 32 + g4 * 8;
            float4 x0 = *(const float4*)p;
            float4 x1 = *(const float4*)(p + 4);
            bf16x8 t;
            t[0] = f2bf(x0.x); t[1] = f2bf(x0.y); t[2] = f2bf(x0.z); t[3] = f2bf(x0.w);
            t[4] = f2bf(x1.x); t[5] = f2bf(x1.y); t[6] = f2bf(x1.z); t[7] = f2bf(x1.w);
            a[kt] = t;
        }
    } else {
        const int m = sec - 1;
        #pragma unroll
        for (int kt = 0; kt < 4; ++kt) {
            const float* p = nfrow + 128 + 3 * (kt * 32 + g4 * 8) + m;
            bf16x8 t;
            #pragma unroll
            for (int e = 0; e < 8; ++e) t[e] = f2bf(p[3 * e]);
            a[kt] = t;
        }
    }
    const short* Wq = (sec == 0) ? Wusp : Wuvp;
    #pragma unroll
    for (int ni = 0; ni < 4; ++ni) {
        const int nt = nth * 4 + ni;
        f32x4 c = {0.f, 0.f, 0.f, 0.f};
        #pragma unroll
        for (int kt = 0; kt < 4; ++kt) {
            bf16x8 b = *(const bf16x8*)(Wq + ((nt * 4 + kt) * 64 + l) * 8);
            c = __builtin_amdgcn_mfma_f32_16x16x32_bf16(a[kt], b, c, 0, 0, 0);
        }
        const int d = nt * 16 + r16;
        #pragma unroll
        for (int r = 0; r < 4; ++r) {
            const int nl = g4 * 4 + r;
            stage[(nl * 128 + d) * 4 + sec] = f2bf(c[r]);
        }
    }
    __syncthreads();
    const uint2* st = (const uint2*)stage;
    uint2* outp = svp + (size_t)n0 * 128;
    #pragma unroll
    for (int j = 0; j < 4; ++j) {
        const int idx = tid + 512 * j;
        outp[idx] = st[idx];
    }
}

// ---------------- K_SCATTER: CSR scatter (separate launch) ------------------
__global__ void k_scatter(const int* __restrict__ ei, int* __restrict__ cursor,
                          const float* __restrict__ edge_attrs,
                          int* __restrict__ elist, int* __restrict__ snds,
                          float4* __restrict__ eas) {
    int e = blockIdx.x * 256 + threadIdx.x;
    if (e < N_EDGES) {
        int snd = ei[e];
        int r = ei[N_EDGES + e];
        int pos = atomicAdd(&cursor[r], 1);
        elist[pos] = e;
        snds[pos] = snd;
        eas[pos] = ((const float4*)edge_attrs)[e];
    }
}

// ---------------- K_EDGE: bf16-MFMA edge MLP (natural order) ----------------
__global__ __launch_bounds__(256) void k_edge(
    const float* __restrict__ edge_feats,
    const float* __restrict__ W1,
    const short* __restrict__ Wp,
    unsigned short* __restrict__ tpw16) {
    __shared__ __align__(16) short h0[64][72];
    __shared__ __align__(16) short h1[64][72];
    __shared__ __align__(16) uint2 stg[4][16][17];

    const short* W2p = Wp;
    const short* W3p = Wp + 4096;
    const short* W4p = Wp + 8192;
    const int tid = threadIdx.x;
    const int l   = tid & 63;
    const int w   = tid >> 6;
    const int r16 = l & 15;
    const int g4  = l >> 4;
    const int base = blockIdx.x * 64;
    const int erow = w * 16 + r16;

    // layer 1 (f32 VALU), natively coalesced edge_feats
    {
        const size_t p = (size_t)(base + erow);
        float4 f0 = ((const float4*)edge_feats)[p * 2 + 0];
        float4 f1 = ((const float4*)edge_feats)[p * 2 + 1];
        float ef[8] = {f0.x, f0.y, f0.z, f0.w, f1.x, f1.y, f1.z, f1.w};
        const int j0 = g4 * 16;
        float acc[16];
        #pragma unroll
        for (int jj = 0; jj < 16; ++jj) acc[jj] = 0.f;
        #pragma unroll
        for (int k = 0; k < 8; ++k) {
            const float* wr = W1 + k * 64 + j0;
            float4 w0 = *(const float4*)(wr + 0);
            float4 w1 = *(const float4*)(wr + 4);
            float4 w2 = *(const float4*)(wr + 8);
            float4 w3 = *(const float4*)(wr + 12);
            const float hk = ef[k];
            acc[0]  = fmaf(hk, w0.x, acc[0]);  acc[1]  = fmaf(hk, w0.y, acc[1]);
            acc[2]  = fmaf(hk, w0.z, acc[2]);  acc[3]  = fmaf(hk, w0.w, acc[3]);
            acc[4]  = fmaf(hk, w1.x, acc[4]);  acc[5]  = fmaf(hk, w1.y, acc[5]);
            acc[6]  = fmaf(hk, w1.z, acc[6]);  acc[7]  = fmaf(hk, w1.w, acc[7]);
            acc[8]  = fmaf(hk, w2.x, acc[8]);  acc[9]  = fmaf(hk, w2.y, acc[9]);
            acc[10] = fmaf(hk, w2.z, acc[10]); acc[11] = fmaf(hk, w2.w, acc[11]);
            acc[12] = fmaf(hk, w3.x, acc[12]); acc[13] = fmaf(hk, w3.y, acc[13]);
            acc[14] = fmaf(hk, w3.z, acc[14]); acc[15] = fmaf(hk, w3.w, acc[15]);
        }
        unsigned pk[8];
        #pragma unroll
        for (int q = 0; q < 8; ++q)
            pk[q] = cvtpk(silu(acc[2*q] * INV_SQRT_RB),
                          silu(acc[2*q + 1] * INV_SQRT_RB));
        uint4 A; A.x = pk[0]; A.y = pk[1]; A.z = pk[2]; A.w = pk[3];
        uint4 B; B.x = pk[4]; B.y = pk[5]; B.z = pk[6]; B.w = pk[7];
        *(uint4*)&h0[erow][j0]     = A;
        *(uint4*)&h0[erow][j0 + 8] = B;
    }

    // layer 2: h0 -> h1
    {
        bf16x8 a0 = *(const bf16x8*)&h0[erow][g4 * 8];
        bf16x8 a1 = *(const bf16x8*)&h0[erow][32 + g4 * 8];
        #pragma unroll
        for (int nt = 0; nt < 4; ++nt) {
            bf16x8 b0 = *(const bf16x8*)(W2p + ((nt * 2 + 0) * 64 + l) * 8);
            bf16x8 b1 = *(const bf16x8*)(W2p + ((nt * 2 + 1) * 64 + l) * 8);
            f32x4 c = {0.f, 0.f, 0.f, 0.f};
            c = __builtin_amdgcn_mfma_f32_16x16x32_bf16(a0, b0, c, 0, 0, 0);
            c = __builtin_amdgcn_mfma_f32_16x16x32_bf16(a1, b1, c, 0, 0, 0);
            unsigned u01 = cvtpk(silu(c[0]), silu(c[1]));
            unsigned u23 = cvtpk(silu(c[2]), silu(c[3]));
            h1[w * 16 + g4 * 4 + 0][nt * 16 + r16] = (short)(u01 & 0xffffu);
            h1[w * 16 + g4 * 4 + 1][nt * 16 + r16] = (short)(u01 >> 16);
            h1[w * 16 + g4 * 4 + 2][nt * 16 + r16] = (short)(u23 & 0xffffu);
            h1[w * 16 + g4 * 4 + 3][nt * 16 + r16] = (short)(u23 >> 16);
        }
    }

    // layer 3: h1 -> h0
    {
        bf16x8 a0 = *(const bf16x8*)&h1[erow][g4 * 8];
        bf16x8 a1 = *(const bf16x8*)&h1[erow][32 + g4 * 8];
        #pragma unroll
        for (int nt = 0; nt < 4; ++nt) {
            bf16x8 b0 = *(const bf16x8*)(W3p + ((nt * 2 + 0) * 64 + l) * 8);
            bf16x8 b1 = *(const bf16x8*)(W3p + ((nt * 2 + 1) * 64 + l) * 8);
            f32x4 c = {0.f, 0.f, 0.f, 0.f};
            c = __builtin_amdgcn_mfma_f32_16x16x32_bf16(a0, b0, c, 0, 0, 0);
            c = __builtin_amdgcn_mfma_f32_16x16x32_bf16(a1, b1, c, 0, 0, 0);
            unsigned u01 = cvtpk(silu(c[0]), silu(c[1]));
            unsigned u23 = cvtpk(silu(c[2]), silu(c[3]));
            h0[w * 16 + g4 * 4 + 0][nt * 16 + r16] = (short)(u01 & 0xffffu);
            h0[w * 16 + g4 * 4 + 1][nt * 16 + r16] = (short)(u01 >> 16);
            h0[w * 16 + g4 * 4 + 2][nt * 16 + r16] = (short)(u23 & 0xffffu);
            h0[w * 16 + g4 * 4 + 3][nt * 16 + r16] = (short)(u23 >> 16);
        }
    }

    // layer 4 (swapped operands) + 16-ch staging -> full-128B-line stores
    {
        bf16x8 ha0 = *(const bf16x8*)&h0[erow][g4 * 8];
        bf16x8 ha1 = *(const bf16x8*)&h0[erow][32 + g4 * 8];
        const int ebase = base + w * 16;
        const int er = (l >> 3) & 7;
        const int ck = l & 7;
        unsigned short* twb0 = tpw16 + (size_t)(ebase + er) * 512 + ck * 8;
        unsigned short* twb1 = tpw16 + (size_t)(ebase + er + 8) * 512 + ck * 8;
        uint2 (*sw)[17] = stg[w];

        #pragma unroll 2
        for (int grp = 0; grp < 8; ++grp) {
            #pragma unroll
            for (int h = 0; h < 4; ++h) {
                const int nt = grp * 4 + h;
                bf16x8 w0 = *(const bf16x8*)(W4p + ((nt * 2 + 0) * 64 + l) * 8);
                bf16x8 w1 = *(const bf16x8*)(W4p + ((nt * 2 + 1) * 64 + l) * 8);
                f32x4 c = {0.f, 0.f, 0.f, 0.f};
                c = __builtin_amdgcn_mfma_f32_16x16x32_bf16(w0, ha0, c, 0, 0, 0);
                c = __builtin_amdgcn_mfma_f32_16x16x32_bf16(w1, ha1, c, 0, 0, 0);
                uint2 u;
                u.x = cvtpk(c[0], c[1]);
                u.y = cvtpk(c[2], c[3]);
                sw[r16][h * 4 + g4] = u;
            }
            uint2 a0 = sw[er][ck * 2];
            uint2 a1 = sw[er][ck * 2 + 1];
            uint2 b0 = sw[er + 8][ck * 2];
            uint2 b1 = sw[er + 8][ck * 2 + 1];
            {
                uint4 v; v.x = a0.x; v.y = a0.y; v.z = a1.x; v.w = a1.y;
                *(uint4*)(twb0 + grp * 64) = v;
            }
            {
                uint4 v; v.x = b0.x; v.y = b0.y; v.z = b1.x; v.w = b1.y;
                *(uint4*)(twb1 + grp * 64) = v;
            }
        }
    }
}

// ---------------- K_GATHER: CSR gather per node -> msg bf16 --------
// msg layout: [s0(128) | s1(128) | v m=0 (256) | m=1 (256) | m=2 (256)]
__global__ __launch_bounds__(128) void k_gather(
    const int*    __restrict__ row,
    const int*    __restrict__ elist,
    const int*    __restrict__ snds,
    const float4* __restrict__ eas,
    const unsigned short* __restrict__ tpw16,
    const uint2*  __restrict__ svp,
    unsigned short* __restrict__ msg16) {
    const int nidx = blockIdx.x;
    const int c = threadIdx.x;      // 128 threads, one channel each
    const int beg = row[nidx];
    const int end = row[nidx + 1];

    float a0 = 0.f, a1 = 0.f, a2 = 0.f, a3 = 0.f,
          a4 = 0.f, a5 = 0.f, a6 = 0.f, a7 = 0.f;

    #pragma unroll 4
    for (int i = beg; i < end; ++i) {
        const int e   = elist[i];
        const int snd = snds[i];
        const float4 ea = eas[i];
        const float y0 = ea.x, y10 = ea.y, y11 = ea.z, y12 = ea.w;

        const uint2 u  = *(const uint2*)(tpw16 + (size_t)e * 512 + c * 4);
        const uint2 sv = svp[(size_t)snd * 128 + c];
        const float t0 = bf2f(u.x & 0xffffu);
        const float t1 = bf2f(u.x >> 16);
        const float t2 = bf2f(u.y & 0xffffu);
        const float t3 = bf2f(u.y >> 16);
        const float se  = bf2f(sv.x & 0xffffu);
        const float ve0 = bf2f(sv.x >> 16);
        const float ve1 = bf2f(sv.y & 0xffffu);
        const float ve2 = bf2f(sv.y >> 16);

        a0 = fmaf(C000 * t0 * y0, se, a0);
        const float dvy = ve0 * y10 + ve1 * y11 + ve2 * y12;
        a1 = fmaf(C110 * t3, dvy, a1);
        const float c011t = C011 * t1 * se;
        a2 = fmaf(c011t, y10, a2);
        a3 = fmaf(c011t, y11, a3);
        a4 = fmaf(c011t, y12, a4);
        const float c101t = C101 * t2 * y0;
        a5 = fmaf(c101t, ve0, a5);
        a6 = fmaf(c101t, ve1, a6);
        a7 = fmaf(c101t, ve2, a7);
    }

    unsigned short* m = msg16 + (size_t)nidx * 1024;
    m[c]       = (unsigned short)f2bf(a0);
    m[128 + c] = (unsigned short)f2bf(a1);
    m[256 + c] = (unsigned short)f2bf(a2);   // v m=0, k=c
    m[512 + c] = (unsigned short)f2bf(a3);   // v m=1
    m[768 + c] = (unsigned short)f2bf(a4);   // v m=2
    m[384 + c] = (unsigned short)f2bf(a5);   // v m=0, k=128+c
    m[640 + c] = (unsigned short)f2bf(a6);
    m[896 + c] = (unsigned short)f2bf(a7);
}

// ---------------- K_NODE_OUT: final node linear, MFMA, 8 waves/block --------
__global__ __launch_bounds__(512) void k_node_out(
    const unsigned short* __restrict__ msg16,
    const short* __restrict__ Wlsp,
    const short* __restrict__ Wlvp,
    float*       __restrict__ out) {
    const int tid = threadIdx.x;
    const int l   = tid & 63;
    const int w   = tid >> 6;
    const int sec = w & 3;           // 0=s, 1..3=v planes
    const int nth = w >> 2;          // nt half: 0 or 1
    const int r16 = l & 15;
    const int g4  = l >> 4;
    const int n0  = blockIdx.x * 16;
    const unsigned short* mrow = msg16 + (size_t)(n0 + r16) * 1024 + sec * 256;

    bf16x8 a[8];
    #pragma unroll
    for (int kt = 0; kt < 8; ++kt)
        a[kt] = *(const bf16x8*)(mrow + kt * 32 + g4 * 8);

    const short* Wq = (sec == 0) ? Wlsp : Wlvp;
    #pragma unroll
    for (int ni = 0; ni < 4; ++ni) {
        const int nt = nth * 4 + ni;
        f32x4 c = {0.f, 0.f, 0.f, 0.f};
        #pragma unroll
        for (int kt = 0; kt < 8; ++kt) {
            bf16x8 b = *(const bf16x8*)(Wq + ((nt * 8 + kt) * 64 + l) * 8);
            c = __builtin_amdgcn_mfma_f32_16x16x32_bf16(a[kt], b, c, 0, 0, 0);
        }
        const int d = nt * 16 + r16;
        #pragma unroll
        for (int r = 0; r < 4; ++r) {
            const size_t n = n0 + g4 * 4 + r;
            if (sec == 0) out[n * 512 + d] = c[r];
            else          out[n * 512 + 128 + 3 * d + (sec - 1)] = c[r];
        }
    }
}

extern "C" void kernel_launch(void* const* d_in, const int* in_sizes, int n_in,
                              void* d_out, int out_size, void* d_ws, size_t ws_size,
                              hipStream_t stream) {
    const float* node_feats = (const float*)d_in[1];
    const float* edge_attrs = (const float*)d_in[2];
    const float* edge_feats = (const float*)d_in[3];
    const int*   edge_index = (const int*)d_in[4];
    const float* W_up_s = (const float*)d_in[5];
    const float* W_up_v = (const float*)d_in[6];
    const float* W_mlp1 = (const float*)d_in[7];
    const float* W_mlp2 = (const float*)d_in[8];
    const float* W_mlp3 = (const float*)d_in[9];
    const float* W_mlp4 = (const float*)d_in[10];
    const float* W_lin_s = (const float*)d_in[11];
    const float* W_lin_v = (const float*)d_in[12];

    float* ws     = (float*)d_ws;
    uint2* svp    = (uint2*)(ws + SVP_OFF);
    unsigned short* msg16 = (unsigned short*)(ws + MSG_OFF);
    short* Wp     = (short*)(ws + WP_OFF);
    short* Wlsp   = Wp + 40960;
    short* Wlvp   = Wp + 73728;
    int*   row    = (int*)(ws + ROW_OFF);
    int*   elist  = (int*)(ws + ELIST_OFF);
    int*   snds   = (int*)(ws + SNDS_OFF);
    float4* eas   = (float4*)(ws + EAS_OFF);
    unsigned short* tpw16 = (unsigned short*)(ws + TPW_OFF);
    // cnt/cursor live in the msg region until k_gather fully overwrites it
    int*   cnt    = (int*)msg16;
    int*   cursor = cnt + N_NODES;
    float* out_f  = (float*)d_out;

    (void)hipMemsetAsync(cnt, 0, 2 * N_NODES * sizeof(int), stream);
    k1_pack_hist<<<K1_PACK + K1_HIST, 512, 0, stream>>>(
        W_mlp2, W_mlp3, W_mlp4, W_lin_s, W_lin_v, W_up_s, W_up_v, Wp,
        edge_index, cnt);
    k2_scan_nodeup<<<1 + 625, 512, 0, stream>>>(
        cnt, row, cursor, node_feats, Wp, svp);
    k_scatter<<<(N_EDGES + 255) / 256, 256, 0, stream>>>(
        edge_index, cursor, edge_attrs, elist, snds, eas);
    k_edge<<<N_EDGES / 64, 256, 0, stream>>>(edge_feats, W_mlp1, Wp, tpw16);
    k_gather<<<N_NODES, 128, 0, stream>>>(row, elist, snds, eas, tpw16, svp, msg16);
    k_node_out<<<625, 512, 0, stream>>>(msg16, Wlsp, Wlvp, out_f);
}

// Round 21
// 187.874 us; speedup vs baseline: 1.0589x; 1.0589x over previous
//
#include <hip/hip_runtime.h>

// MACE node message block. All-MFMA, bf16 intermediates, cvt_pk.
// 7 GPU ops: memset -> k1(pack|hist) -> k2(scan|node_up) -> k_scatter(efs)
// -> k_edge_mfma(sorted efs) -> k_gather -> k_node_out.
// R21 = R19's merged front end + R17's exact scatter/edge/gather trio
// (R20 lesson: "equivalent" re-plumbed source != equivalent codegen; the
//  efs-based edge kernel compiled to 48 VGPR and ran 63-66us; keep it).
// N=10000, E=160000, C=128, RB=8, HID=64.
//
// ws layout (float units):
//   [0 .. 2.56M)        svp (N,128) uint2 packed bf16 [se,ve0|ve1,ve2]
//   [2.56M .. 7.68M)    msg (N,1024) bf16; cnt/cursor ints live here pre-gather
//   [7.68M .. +69632)   packed bf16 weights: W2p W3p W4p Wlsp Wlvp Wusp Wuvp
//   [7749632 +10001]    row (int)
//   [7759636 +160000]   elist (int, unused; kept for layout stability)
//   [7919636 +160000]   snds (int)
//   [8079636 +640000]   eas (float4)
//   [8719636 +1280000]  efs (2x float4 per sorted pos)
//   [9999636 +20.48Mf)  tpw [pos][512] bf16 (164 MB)

#define N_NODES 10000
#define N_EDGES 160000

#define SVP_OFF    0u
#define MSG_OFF    2560000u
#define WP_OFF     7680000u
#define ROW_OFF    7749632u
#define ELIST_OFF  7759636u
#define SNDS_OFF   7919636u
#define EAS_OFF    8079636u
#define EFS_OFF    8719636u
#define TPW_OFF    9999636u

// k1 block partition (512 threads each)
#define K1_PACK    272                  // 272*512 = 139264 pack elements
#define K1_HIST    313                  // 313*512 >= 160000

typedef __attribute__((ext_vector_type(8))) short bf16x8;
typedef __attribute__((ext_vector_type(4))) float f32x4;

__device__ __forceinline__ float silu(float x) {
    return x / (1.0f + __expf(-x));
}
__device__ __forceinline__ short f2bf(float x) {
    unsigned u = __float_as_uint(x);
    unsigned r = (u + 0x7FFFu + ((u >> 16) & 1u)) >> 16;
    return (short)r;
}
// HW packed f32->bf16 (RNE), single instruction; no builtin on gfx950.
__device__ __forceinline__ unsigned cvtpk(float lo, float hi) {
    unsigned r;
    asm("v_cvt_pk_bf16_f32 %0, %1, %2" : "=v"(r) : "v"(lo), "v"(hi));
    return r;
}
__device__ __forceinline__ float bf2f(unsigned h) {
    return __uint_as_float(h << 16);
}

constexpr float INV_SQRT_C  = 0.08838834764831845f;
constexpr float INV_SQRT_RB = 0.35355339059327373f;
constexpr float INV_SQRT_H  = 0.125f;
constexpr float OUT_SCALE   = 0.0625f * 0.0625f;      // 1/sqrt(256) / AVG_NEIGH
constexpr float C000 = 0.7071067811865476f;
constexpr float C110 = 0.4082482904638631f;
constexpr float C011 = 0.7071067811865476f;
constexpr float C101 = 0.7071067811865476f;

// ---------------- K1: pack | hist ----------
// shorts: W2p[0,4096) W3p[4096,8192) W4p[8192,40960) Wlsp[40960,73728)
//         Wlvp[73728,106496) Wusp[106496,122880) Wuvp[122880,139264)
__global__ __launch_bounds__(512) void k1_pack_hist(
    const float* __restrict__ W2, const float* __restrict__ W3,
    const float* __restrict__ W4,
    const float* __restrict__ Wls, const float* __restrict__ Wlv,
    const float* __restrict__ Wus, const float* __restrict__ Wuv,
    short* __restrict__ Wp,
    const int* __restrict__ ei, int* __restrict__ cnt) {
    const int bid = blockIdx.x;
    const int tid = threadIdx.x;

    if (bid < K1_PACK) {
        int idx = bid * 512 + tid;          // < 139264
        if (idx < 4096) {
            int i2 = idx;
            int e = i2 & 7, l = (i2 >> 3) & 63, kt = (i2 >> 9) & 1, nt = i2 >> 10;
            int k = kt * 32 + (l >> 4) * 8 + e;
            int col = nt * 16 + (l & 15);
            Wp[idx] = f2bf(W2[k * 64 + col] * INV_SQRT_H);
        } else if (idx < 8192) {
            int i2 = idx - 4096;
            int e = i2 & 7, l = (i2 >> 3) & 63, kt = (i2 >> 9) & 1, nt = i2 >> 10;
            int k = kt * 32 + (l >> 4) * 8 + e;
            int col = nt * 16 + (l & 15);
            Wp[idx] = f2bf(W3[k * 64 + col] * INV_SQRT_H);
        } else if (idx < 40960) {
            int i2 = idx - 8192;
            int e = i2 & 7, l = (i2 >> 3) & 63, kt = (i2 >> 9) & 1, nt = i2 >> 10;
            int k = kt * 32 + (l >> 4) * 8 + e;
            int o = nt * 16 + (l & 15);      // o = c*4 + a
            int c = o >> 2, a = o & 3;
            Wp[idx] = f2bf(W4[k * 512 + a * 128 + c] * INV_SQRT_H);
        } else if (idx < 73728) {
            int i2 = idx - 40960;
            int e = i2 & 7, l = (i2 >> 3) & 63, kt = (i2 >> 9) & 7, nt = (i2 >> 12) & 7;
            int k = kt * 32 + (l >> 4) * 8 + e;
            int d = nt * 16 + (l & 15);
            Wp[idx] = f2bf(Wls[k * 128 + d] * OUT_SCALE);
        } else if (idx < 106496) {
            int i2 = idx - 73728;
            int e = i2 & 7, l = (i2 >> 3) & 63, kt = (i2 >> 9) & 7, nt = (i2 >> 12) & 7;
            int k = kt * 32 + (l >> 4) * 8 + e;
            int d = nt * 16 + (l & 15);
            Wp[idx] = f2bf(Wlv[k * 128 + d] * OUT_SCALE);
        } else if (idx < 122880) {
            int i2 = idx - 106496;
            int e = i2 & 7, l = (i2 >> 3) & 63, kt = (i2 >> 9) & 3, nt = (i2 >> 11) & 7;
            int k = kt * 32 + (l >> 4) * 8 + e;
            int d = nt * 16 + (l & 15);
            Wp[idx] = f2bf(Wus[k * 128 + d] * INV_SQRT_C);
        } else if (idx < 139264) {
            int i2 = idx - 122880;
            int e = i2 & 7, l = (i2 >> 3) & 63, kt = (i2 >> 9) & 3, nt = (i2 >> 11) & 7;
            int k = kt * 32 + (l >> 4) * 8 + e;
            int d = nt * 16 + (l & 15);
            Wp[idx] = f2bf(Wuv[k * 128 + d] * INV_SQRT_C);
        }
        return;
    }
    // ---- receiver histogram
    int e = (bid - K1_PACK) * 512 + tid;
    if (e < N_EDGES) atomicAdd(&cnt[ei[N_EDGES + e]], 1);
}

// ---------------- K2: scan (block 0) | node_up (blocks 1..625) --------------
__global__ __launch_bounds__(512) void k2_scan_nodeup(
    const int*   __restrict__ cnt,
    int*         __restrict__ row,
    int*         __restrict__ cursor,
    const float* __restrict__ nf,
    const short* __restrict__ Wp,
    uint2*       __restrict__ svp) {
    __shared__ __align__(8) short stage[16 * 128 * 4];   // 16KB (scan reuses as int)
    const int bid = blockIdx.x;
    const int tid = threadIdx.x;

    if (bid == 0) {
        int* part = (int*)stage;
        const int t = tid;
        const int base = t * 20;
        int s = 0;
        #pragma unroll
        for (int i = 0; i < 20; ++i) {
            int idx = base + i;
            s += (idx < N_NODES) ? cnt[idx] : 0;
        }
        part[t] = s;
        __syncthreads();
        for (int off = 1; off < 512; off <<= 1) {
            int v = (t >= off) ? part[t - off] : 0;
            __syncthreads();
            part[t] += v;
            __syncthreads();
        }
        int run = part[t] - s;   // exclusive prefix
        #pragma unroll
        for (int i = 0; i < 20; ++i) {
            int idx = base + i;
            if (idx < N_NODES) {
                row[idx] = run;
                cursor[idx] = run;
                run += cnt[idx];
            }
        }
        if (t == 511) row[N_NODES] = part[511];
        return;
    }

    // ---- node up-projection (MFMA) -> svp
    const short* Wusp = Wp + 106496;
    const short* Wuvp = Wp + 122880;
    const int l   = tid & 63;
    const int w   = tid >> 6;
    const int sec = w & 3;
    const int nth = w >> 2;
    const int r16 = l & 15;
    const int g4  = l >> 4;
    const int n0  = (bid - 1) * 16;
    const float* nfrow = nf + (size_t)(n0 + r16) * 512;

    bf16x8 a[4];
    if (sec == 0) {
        #pragma unroll
        for (int kt = 0; kt < 4; ++kt) {
            const float* p = nfrow + kt * 32 + g4 * 8;
            float4 x0 = *(const float4*)p;
            float4 x1 = *(const float4*)(p + 4);
            bf16x8 t;
            t[0] = f2bf(x0.x); t[1] = f2bf(x0.y); t[2] = f2bf(x0.z); t[3] = f2bf(x0.w);
            t[4] = f2bf(x1.x); t[5] = f2bf(x1.y); t[6] = f2bf(x1.z); t[7] = f2bf(x1.w);
            a[kt] = t;
        }
    } else {
        const int m = sec - 1;
        #pragma unroll
        for (int kt = 0; kt < 4; ++kt) {
            const float* p = nfrow + 128 + 3 * (kt * 32 + g4 * 8) + m;
            bf16x8 t;
            #pragma unroll
            for (int e = 0; e < 8; ++e) t[e] = f2bf(p[3 * e]);
            a[kt] = t;
        }
    }
    const short* Wq = (sec == 0) ? Wusp : Wuvp;
    #pragma unroll
    for (int ni = 0; ni < 4; ++ni) {
        const int nt = nth * 4 + ni;
        f32x4 c = {0.f, 0.f, 0.f, 0.f};
        #pragma unroll
        for (int kt = 0; kt < 4; ++kt) {
            bf16x8 b = *(const bf16x8*)(Wq + ((nt * 4 + kt) * 64 + l) * 8);
            c = __builtin_amdgcn_mfma_f32_16x16x32_bf16(a[kt], b, c, 0, 0, 0);
        }
        const int d = nt * 16 + r16;
        #pragma unroll
        for (int r = 0; r < 4; ++r) {
            const int nl = g4 * 4 + r;
            stage[(nl * 128 + d) * 4 + sec] = f2bf(c[r]);
        }
    }
    __syncthreads();
    const uint2* st = (const uint2*)stage;
    uint2* outp = svp + (size_t)n0 * 128;
    #pragma unroll
    for (int j = 0; j < 4; ++j) {
        const int idx = tid + 512 * j;
        outp[idx] = st[idx];
    }
}

// ---------------- K_SCATTER: CSR scatter + efs pre-gather (R17 exact) -------
__global__ void k_scatter(const int* __restrict__ ei, int* __restrict__ cursor,
                          const float* __restrict__ edge_attrs,
                          const float* __restrict__ edge_feats,
                          int* __restrict__ snds,
                          float4* __restrict__ eas, float4* __restrict__ efs) {
    int e = blockIdx.x * 256 + threadIdx.x;
    if (e < N_EDGES) {
        int snd = ei[e];
        int r = ei[N_EDGES + e];
        int pos = atomicAdd(&cursor[r], 1);
        snds[pos] = snd;
        eas[pos] = ((const float4*)edge_attrs)[e];
        efs[(size_t)pos * 2 + 0] = ((const float4*)edge_feats)[(size_t)e * 2 + 0];
        efs[(size_t)pos * 2 + 1] = ((const float4*)edge_feats)[(size_t)e * 2 + 1];
    }
}

// ---------------- K_EDGE: bf16-MFMA edge MLP (R17 exact) --------------------
// Layer 4: 16-channel staging per phase; each wave stores full 128B lines.
__global__ __launch_bounds__(256) void k_edge_mfma(
    const float4* __restrict__ efs,
    const float* __restrict__ W1,
    const short* __restrict__ W2p,
    const short* __restrict__ W3p,
    const short* __restrict__ W4p,
    int ne,
    unsigned short* __restrict__ tpw16) {
    __shared__ __align__(16) short h0[64][72];   // padded: 2-way banks only
    __shared__ __align__(16) short h1[64][72];
    __shared__ __align__(16) uint2 stg[4][16][17]; // [wave][edge][ch_slot+pad]

    const int tid = threadIdx.x;
    const int l   = tid & 63;
    const int w   = tid >> 6;
    const int r16 = l & 15;
    const int g4  = l >> 4;
    const int base = blockIdx.x * 64;
    const int erow = w * 16 + r16;               // this lane's edge row

    // ---- layer 1 (f32 VALU), coalesced efs reads
    {
        const int pos = base + erow;
        const size_t p = (size_t)((pos < ne) ? pos : 0);
        float4 f0 = efs[p * 2 + 0];
        float4 f1 = efs[p * 2 + 1];
        float ef[8] = {f0.x, f0.y, f0.z, f0.w, f1.x, f1.y, f1.z, f1.w};
        const int j0 = g4 * 16;
        float acc[16];
        #pragma unroll
        for (int jj = 0; jj < 16; ++jj) acc[jj] = 0.f;
        #pragma unroll
        for (int k = 0; k < 8; ++k) {
            const float* wr = W1 + k * 64 + j0;
            float4 w0 = *(const float4*)(wr + 0);
            float4 w1 = *(const float4*)(wr + 4);
            float4 w2 = *(const float4*)(wr + 8);
            float4 w3 = *(const float4*)(wr + 12);
            const float hk = ef[k];
            acc[0]  = fmaf(hk, w0.x, acc[0]);  acc[1]  = fmaf(hk, w0.y, acc[1]);
            acc[2]  = fmaf(hk, w0.z, acc[2]);  acc[3]  = fmaf(hk, w0.w, acc[3]);
            acc[4]  = fmaf(hk, w1.x, acc[4]);  acc[5]  = fmaf(hk, w1.y, acc[5]);
            acc[6]  = fmaf(hk, w1.z, acc[6]);  acc[7]  = fmaf(hk, w1.w, acc[7]);
            acc[8]  = fmaf(hk, w2.x, acc[8]);  acc[9]  = fmaf(hk, w2.y, acc[9]);
            acc[10] = fmaf(hk, w2.z, acc[10]); acc[11] = fmaf(hk, w2.w, acc[11]);
            acc[12] = fmaf(hk, w3.x, acc[12]); acc[13] = fmaf(hk, w3.y, acc[13]);
            acc[14] = fmaf(hk, w3.z, acc[14]); acc[15] = fmaf(hk, w3.w, acc[15]);
        }
        unsigned pk[8];
        #pragma unroll
        for (int q = 0; q < 8; ++q)
            pk[q] = cvtpk(silu(acc[2*q] * INV_SQRT_RB),
                          silu(acc[2*q + 1] * INV_SQRT_RB));
        uint4 A; A.x = pk[0]; A.y = pk[1]; A.z = pk[2]; A.w = pk[3];
        uint4 B; B.x = pk[4]; B.y = pk[5]; B.z = pk[6]; B.w = pk[7];
        *(uint4*)&h0[erow][j0]     = A;
        *(uint4*)&h0[erow][j0 + 8] = B;
    }

    // ---- layer 2: h0 -> h1
    {
        bf16x8 a0 = *(const bf16x8*)&h0[erow][g4 * 8];
        bf16x8 a1 = *(const bf16x8*)&h0[erow][32 + g4 * 8];
        #pragma unroll
        for (int nt = 0; nt < 4; ++nt) {
            bf16x8 b0 = *(const bf16x8*)(W2p + ((nt * 2 + 0) * 64 + l) * 8);
            bf16x8 b1 = *(const bf16x8*)(W2p + ((nt * 2 + 1) * 64 + l) * 8);
            f32x4 c = {0.f, 0.f, 0.f, 0.f};
            c = __builtin_amdgcn_mfma_f32_16x16x32_bf16(a0, b0, c, 0, 0, 0);
            c = __builtin_amdgcn_mfma_f32_16x16x32_bf16(a1, b1, c, 0, 0, 0);
            unsigned u01 = cvtpk(silu(c[0]), silu(c[1]));
            unsigned u23 = cvtpk(silu(c[2]), silu(c[3]));
            h1[w * 16 + g4 * 4 + 0][nt * 16 + r16] = (short)(u01 & 0xffffu);
            h1[w * 16 + g4 * 4 + 1][nt * 16 + r16] = (short)(u01 >> 16);
            h1[w * 16 + g4 * 4 + 2][nt * 16 + r16] = (short)(u23 & 0xffffu);
            h1[w * 16 + g4 * 4 + 3][nt * 16 + r16] = (short)(u23 >> 16);
        }
    }

    // ---- layer 3: h1 -> h0
    {
        bf16x8 a0 = *(const bf16x8*)&h1[erow][g4 * 8];
        bf16x8 a1 = *(const bf16x8*)&h1[erow][32 + g4 * 8];
        #pragma unroll
        for (int nt = 0; nt < 4; ++nt) {
            bf16x8 b0 = *(const bf16x8*)(W3p + ((nt * 2 + 0) * 64 + l) * 8);
            bf16x8 b1 = *(const bf16x8*)(W3p + ((nt * 2 + 1) * 64 + l) * 8);
            f32x4 c = {0.f, 0.f, 0.f, 0.f};
            c = __builtin_amdgcn_mfma_f32_16x16x32_bf16(a0, b0, c, 0, 0, 0);
            c = __builtin_amdgcn_mfma_f32_16x16x32_bf16(a1, b1, c, 0, 0, 0);
            unsigned u01 = cvtpk(silu(c[0]), silu(c[1]));
            unsigned u23 = cvtpk(silu(c[2]), silu(c[3]));
            h0[w * 16 + g4 * 4 + 0][nt * 16 + r16] = (short)(u01 & 0xffffu);
            h0[w * 16 + g4 * 4 + 1][nt * 16 + r16] = (short)(u01 >> 16);
            h0[w * 16 + g4 * 4 + 2][nt * 16 + r16] = (short)(u23 & 0xffffu);
            h0[w * 16 + g4 * 4 + 3][nt * 16 + r16] = (short)(u23 >> 16);
        }
    }

    // ---- layer 4 (swapped operands) + 16-ch staging -> full-128B-line stores
    {
        bf16x8 ha0 = *(const bf16x8*)&h0[erow][g4 * 8];
        bf16x8 ha1 = *(const bf16x8*)&h0[erow][32 + g4 * 8];
        const int ebase = base + w * 16;
        const int er = (l >> 3) & 7;
        const int ck = l & 7;
        const bool v0 = (ebase + er) < ne;
        const bool v1 = (ebase + er + 8) < ne;
        unsigned short* twb0 = tpw16 + (size_t)(ebase + er) * 512 + ck * 8;
        unsigned short* twb1 = tpw16 + (size_t)(ebase + er + 8) * 512 + ck * 8;
        uint2 (*sw)[17] = stg[w];

        #pragma unroll 2
        for (int grp = 0; grp < 8; ++grp) {
            #pragma unroll
            for (int h = 0; h < 4; ++h) {
                const int nt = grp * 4 + h;
                bf16x8 w0 = *(const bf16x8*)(W4p + ((nt * 2 + 0) * 64 + l) * 8);
                bf16x8 w1 = *(const bf16x8*)(W4p + ((nt * 2 + 1) * 64 + l) * 8);
                f32x4 c = {0.f, 0.f, 0.f, 0.f};
                c = __builtin_amdgcn_mfma_f32_16x16x32_bf16(w0, ha0, c, 0, 0, 0);
                c = __builtin_amdgcn_mfma_f32_16x16x32_bf16(w1, ha1, c, 0, 0, 0);
                uint2 u;
                u.x = cvtpk(c[0], c[1]);
                u.y = cvtpk(c[2], c[3]);
                sw[r16][h * 4 + g4] = u;
            }
            // wave-internal staging; compiler inserts lgkmcnt before reads
            uint2 a0 = sw[er][ck * 2];
            uint2 a1 = sw[er][ck * 2 + 1];
            uint2 b0 = sw[er + 8][ck * 2];
            uint2 b1 = sw[er + 8][ck * 2 + 1];
            if (v0) {
                uint4 v; v.x = a0.x; v.y = a0.y; v.z = a1.x; v.w = a1.y;
                *(uint4*)(twb0 + grp * 64) = v;
            }
            if (v1) {
                uint4 v; v.x = b0.x; v.y = b0.y; v.z = b1.x; v.w = b1.y;
                *(uint4*)(twb1 + grp * 64) = v;
            }
        }
    }
}

// ---------------- K_GATHER: CSR gather per node -> msg bf16 (R17 exact) -----
// msg layout: [s0(128) | s1(128) | v m=0 (256) | m=1 (256) | m=2 (256)]
__global__ __launch_bounds__(128) void k_gather(
    const int*    __restrict__ row,
    const int*    __restrict__ snds,
    const float4* __restrict__ eas,
    const unsigned short* __restrict__ tpw16,
    const uint2*  __restrict__ svp,
    unsigned short* __restrict__ msg16) {
    const int nidx = blockIdx.x;
    const int c = threadIdx.x;      // 128 threads, one channel each
    const int beg = row[nidx];
    const int end = row[nidx + 1];

    float a0 = 0.f, a1 = 0.f, a2 = 0.f, a3 = 0.f,
          a4 = 0.f, a5 = 0.f, a6 = 0.f, a7 = 0.f;

    #pragma unroll 4
    for (int i = beg; i < end; ++i) {
        const int snd = snds[i];
        const float4 ea = eas[i];
        const float y0 = ea.x, y10 = ea.y, y11 = ea.z, y12 = ea.w;

        const uint2 u  = *(const uint2*)(tpw16 + (size_t)i * 512 + c * 4);
        const uint2 sv = svp[(size_t)snd * 128 + c];
        const float t0 = bf2f(u.x & 0xffffu);
        const float t1 = bf2f(u.x >> 16);
        const float t2 = bf2f(u.y & 0xffffu);
        const float t3 = bf2f(u.y >> 16);
        const float se  = bf2f(sv.x & 0xffffu);
        const float ve0 = bf2f(sv.x >> 16);
        const float ve1 = bf2f(sv.y & 0xffffu);
        const float ve2 = bf2f(sv.y >> 16);

        a0 = fmaf(C000 * t0 * y0, se, a0);
        const float dvy = ve0 * y10 + ve1 * y11 + ve2 * y12;
        a1 = fmaf(C110 * t3, dvy, a1);
        const float c011t = C011 * t1 * se;
        a2 = fmaf(c011t, y10, a2);
        a3 = fmaf(c011t, y11, a3);
        a4 = fmaf(c011t, y12, a4);
        const float c101t = C101 * t2 * y0;
        a5 = fmaf(c101t, ve0, a5);
        a6 = fmaf(c101t, ve1, a6);
        a7 = fmaf(c101t, ve2, a7);
    }

    unsigned short* m = msg16 + (size_t)nidx * 1024;
    m[c]       = (unsigned short)f2bf(a0);
    m[128 + c] = (unsigned short)f2bf(a1);
    m[256 + c] = (unsigned short)f2bf(a2);   // v m=0, k=c
    m[512 + c] = (unsigned short)f2bf(a3);   // v m=1
    m[768 + c] = (unsigned short)f2bf(a4);   // v m=2
    m[384 + c] = (unsigned short)f2bf(a5);   // v m=0, k=128+c
    m[640 + c] = (unsigned short)f2bf(a6);
    m[896 + c] = (unsigned short)f2bf(a7);
}

// ---------------- K_NODE_OUT: final node linear, MFMA, 8 waves/block --------
__global__ __launch_bounds__(512) void k_node_out(
    const unsigned short* __restrict__ msg16,
    const short* __restrict__ Wlsp,
    const short* __restrict__ Wlvp,
    float*       __restrict__ out) {
    const int tid = threadIdx.x;
    const int l   = tid & 63;
    const int w   = tid >> 6;
    const int sec = w & 3;           // 0=s, 1..3=v planes
    const int nth = w >> 2;          // nt half: 0 or 1
    const int r16 = l & 15;
    const int g4  = l >> 4;
    const int n0  = blockIdx.x * 16;
    const unsigned short* mrow = msg16 + (size_t)(n0 + r16) * 1024 + sec * 256;

    bf16x8 a[8];
    #pragma unroll
    for (int kt = 0; kt < 8; ++kt)
        a[kt] = *(const bf16x8*)(mrow + kt * 32 + g4 * 8);

    const short* Wq = (sec == 0) ? Wlsp : Wlvp;
    #pragma unroll
    for (int ni = 0; ni < 4; ++ni) {
        const int nt = nth * 4 + ni;
        f32x4 c = {0.f, 0.f, 0.f, 0.f};
        #pragma unroll
        for (int kt = 0; kt < 8; ++kt) {
            bf16x8 b = *(const bf16x8*)(Wq + ((nt * 8 + kt) * 64 + l) * 8);
            c = __builtin_amdgcn_mfma_f32_16x16x32_bf16(a[kt], b, c, 0, 0, 0);
        }
        const int d = nt * 16 + r16;
        #pragma unroll
        for (int r = 0; r < 4; ++r) {
            const size_t n = n0 + g4 * 4 + r;
            if (sec == 0) out[n * 512 + d] = c[r];
            else          out[n * 512 + 128 + 3 * d + (sec - 1)] = c[r];
        }
    }
}

extern "C" void kernel_launch(void* const* d_in, const int* in_sizes, int n_in,
                              void* d_out, int out_size, void* d_ws, size_t ws_size,
                              hipStream_t stream) {
    const float* node_feats = (const float*)d_in[1];
    const float* edge_attrs = (const float*)d_in[2];
    const float* edge_feats = (const float*)d_in[3];
    const int*   edge_index = (const int*)d_in[4];
    const float* W_up_s = (const float*)d_in[5];
    const float* W_up_v = (const float*)d_in[6];
    const float* W_mlp1 = (const float*)d_in[7];
    const float* W_mlp2 = (const float*)d_in[8];
    const float* W_mlp3 = (const float*)d_in[9];
    const float* W_mlp4 = (const float*)d_in[10];
    const float* W_lin_s = (const float*)d_in[11];
    const float* W_lin_v = (const float*)d_in[12];

    float* ws     = (float*)d_ws;
    uint2* svp    = (uint2*)(ws + SVP_OFF);
    unsigned short* msg16 = (unsigned short*)(ws + MSG_OFF);
    short* Wp     = (short*)(ws + WP_OFF);
    short* W2p    = Wp;                      // 4096
    short* W3p    = Wp + 4096;               // 4096
    short* W4p    = Wp + 8192;               // 32768
    short* Wlsp   = Wp + 40960;              // 32768
    short* Wlvp   = Wp + 73728;              // 32768
    int*   row    = (int*)(ws + ROW_OFF);
    int*   snds   = (int*)(ws + SNDS_OFF);
    float4* eas   = (float4*)(ws + EAS_OFF);
    float4* efs   = (float4*)(ws + EFS_OFF);
    unsigned short* tpw16 = (unsigned short*)(ws + TPW_OFF);
    // cnt/cursor live in the msg region until k_gather fully overwrites it
    int*   cnt    = (int*)msg16;
    int*   cursor = cnt + N_NODES;
    float* out_f  = (float*)d_out;

    (void)hipMemsetAsync(cnt, 0, 2 * N_NODES * sizeof(int), stream);
    k1_pack_hist<<<K1_PACK + K1_HIST, 512, 0, stream>>>(
        W_mlp2, W_mlp3, W_mlp4, W_lin_s, W_lin_v, W_up_s, W_up_v, Wp,
        edge_index, cnt);
    k2_scan_nodeup<<<1 + 625, 512, 0, stream>>>(
        cnt, row, cursor, node_feats, Wp, svp);
    k_scatter<<<(N_EDGES + 255) / 256, 256, 0, stream>>>(
        edge_index, cursor, edge_attrs, edge_feats, snds, eas, efs);
    k_edge_mfma<<<(N_EDGES + 63) / 64, 256, 0, stream>>>(
        efs, W_mlp1, W2p, W3p, W4p, N_EDGES, tpw16);
    k_gather<<<N_NODES, 128, 0, stream>>>(row, snds, eas, tpw16, svp, msg16);
    k_node_out<<<625, 512, 0, stream>>>(msg16, Wlsp, Wlvp, out_f);
}